// Round 2
// baseline (15000.880 us; speedup 1.0000x reference)
//
#include <hip/hip_runtime.h>
#include <hip/hip_bf16.h>

// Problem constants
#define BB 32
#define SS 512
#define DD 256
#define HH 256
#define GG 1024          // 4*H
#define MM (SS*BB)       // 16384 rows, m = s*32 + b
#define NSENT 16
#define TT 12
#define TAG_START 10
#define TAG_STOP 11

__device__ __forceinline__ float sigm(float x) { return 1.f / (1.f + expf(-x)); }

// ---------------- embed gather: X1[m][d] = embed[inputs[b][s]][d], m = s*32+b
__global__ void embed_kernel(const int* __restrict__ toks, const float* __restrict__ emb,
                             float* __restrict__ X1) {
  int m = blockIdx.x;
  int s = m >> 5, b = m & 31;
  int tok = toks[b * SS + s];
  ((float4*)(X1 + (size_t)m * DD))[threadIdx.x] =
      ((const float4*)(emb + (size_t)tok * DD))[threadIdx.x];
}

// ---------------- fp32 NT GEMM: C[M,N] = A[M,K] @ W[N,K]^T + bias, 64x64 tile
__launch_bounds__(256)
__global__ void gemm_nt(const float* __restrict__ A, const float* __restrict__ W,
                        const float* __restrict__ bias, float* __restrict__ C,
                        int K, int ldC) {
  __shared__ float As[16 * 64];
  __shared__ float Ws[16 * 64];
  const int tid = threadIdx.x;
  const int n0 = blockIdx.x * 64, m0 = blockIdx.y * 64;
  const int row = tid >> 2, q = tid & 3;
  const int tn = tid & 15, tm = tid >> 4;
  float acc[4][4] = {};
  for (int kk = 0; kk < K; kk += 16) {
    float4 a = *(const float4*)(A + (size_t)(m0 + row) * K + kk + q * 4);
    float4 w = *(const float4*)(W + (size_t)(n0 + row) * K + kk + q * 4);
    As[(q * 4 + 0) * 64 + row] = a.x; As[(q * 4 + 1) * 64 + row] = a.y;
    As[(q * 4 + 2) * 64 + row] = a.z; As[(q * 4 + 3) * 64 + row] = a.w;
    Ws[(q * 4 + 0) * 64 + row] = w.x; Ws[(q * 4 + 1) * 64 + row] = w.y;
    Ws[(q * 4 + 2) * 64 + row] = w.z; Ws[(q * 4 + 3) * 64 + row] = w.w;
    __syncthreads();
#pragma unroll
    for (int kl = 0; kl < 16; ++kl) {
      const float4 av = *(const float4*)(As + kl * 64 + tm * 4);
      const float4 wv = *(const float4*)(Ws + kl * 64 + tn * 4);
      const float am[4] = {av.x, av.y, av.z, av.w};
      const float wm[4] = {wv.x, wv.y, wv.z, wv.w};
#pragma unroll
      for (int i = 0; i < 4; ++i)
#pragma unroll
        for (int j = 0; j < 4; ++j) acc[i][j] = fmaf(am[i], wm[j], acc[i][j]);
    }
    __syncthreads();
  }
  float4 bz = make_float4(0.f, 0.f, 0.f, 0.f);
  if (bias) bz = *(const float4*)(bias + n0 + tn * 4);
#pragma unroll
  for (int i = 0; i < 4; ++i) {
    float4 o = make_float4(acc[i][0] + bz.x, acc[i][1] + bz.y,
                           acc[i][2] + bz.z, acc[i][3] + bz.w);
    *(float4*)(C + (size_t)(m0 + tm * 4 + i) * ldC + n0 + tn * 4) = o;
  }
}

// ---------------- whh repack: whh_p[dir][slice][k][r] = whh[dir][g][k],
//                  r = gate*32 + j, g = gate*256 + slice*32 + j
__global__ void prep_whh(const float* __restrict__ whh, float* __restrict__ out) {
  int idx = blockIdx.x * 256 + threadIdx.x;        // 2*8*256*128 = 524288
  int r = idx & 127;
  int k = (idx >> 7) & 255;
  int sl = (idx >> 15) & 7;
  int dir = idx >> 18;
  int g = (r >> 5) * 256 + sl * 32 + (r & 31);
  out[idx] = whh[(size_t)(dir * GG + g) * HH + k];
}

// ---------------- LSTM recurrence (one layer, both dirs).
// grid = 256: bid = (dir + 2*bg) + 32*slice  -> 8-wg sync group (dir,bg) on one XCD
// (if bid%8 round-robin holds; correctness is agent-scope so mapping only affects speed).
// Each wg: 2 batches (bg*2, bg*2+1), 32 hidden units (slice), whh slice resident in LDS.
// 134400 B static LDS -> exactly 1 wg/CU -> 256 wgs co-resident on 256 CUs.
__launch_bounds__(128)
__global__ void rec_kernel(const float* __restrict__ Xp, const float* __restrict__ whh_p,
                           float* __restrict__ hist, float* __restrict__ h_buf,
                           int* __restrict__ flags) {
  __shared__ float lds[33600];       // 134400 bytes static
  float* whh_lds = lds;              // [k*128 + r], 32768 floats
  float* h_lds = lds + 32768;        // [k*2 + c],   512
  float* g_lds = lds + 33280;        // [r*2 + c],   256
  float* c_lds = lds + 33536;        // [j*2 + c],   64
  const int tid = threadIdx.x;
  const int bid = blockIdx.x;
  const int slice = bid >> 5;
  const int db = bid & 31;
  const int dir = db & 1;
  const int bg = db >> 1;
  const float* wp = whh_p + (size_t)(dir * 8 + slice) * 256 * 128;
  for (int i = tid; i < 32768; i += 128) whh_lds[i] = wp[i];
  if (tid < 64) c_lds[tid] = 0.f;
  int* fl = flags + (dir * 16 + bg) * 8 * 16;      // 16-int padded flags
  const float* XpD = Xp + (size_t)dir * MM * GG;
  const int gate = tid >> 5, j = tid & 31;
  const int gcol = gate * 256 + slice * 32 + j;
  __syncthreads();
  for (int t = 0; t < SS; ++t) {
    const int s = dir ? (SS - 1 - t) : t;
    if (tid < 8) {
      while (__hip_atomic_load(fl + tid * 16, __ATOMIC_ACQUIRE, __HIP_MEMORY_SCOPE_AGENT) < t)
        __builtin_amdgcn_s_sleep(1);
    }
    __syncthreads();
    const int slotR = (t & 1) ^ 1;                 // slot holding h_{t-1}
    for (int i = tid; i < 512; i += 128) {
      const int c = i >> 8, k = i & 255;
      float v = __hip_atomic_load(
          h_buf + ((size_t)(slotR * 2 + dir) * 32 + bg * 2 + c) * HH + k,
          __ATOMIC_RELAXED, __HIP_MEMORY_SCOPE_AGENT);
      h_lds[k * 2 + c] = v;
    }
    __syncthreads();
    const int m0 = s * BB + bg * 2;
    const float xp0 = XpD[(size_t)m0 * GG + gcol];
    const float xp1 = XpD[(size_t)(m0 + 1) * GG + gcol];
    float acc0 = 0.f, acc1 = 0.f;
#pragma unroll 8
    for (int k = 0; k < 256; ++k) {
      const float w = whh_lds[k * 128 + tid];
      acc0 = fmaf(w, h_lds[2 * k], acc0);
      acc1 = fmaf(w, h_lds[2 * k + 1], acc1);
    }
    g_lds[tid * 2] = acc0 + xp0;
    g_lds[tid * 2 + 1] = acc1 + xp1;
    __syncthreads();
    if (tid < 64) {
      const int j2 = tid >> 1, c = tid & 1;
      const float iv = g_lds[(j2) * 2 + c];
      const float fv = g_lds[(32 + j2) * 2 + c];
      const float gv = g_lds[(64 + j2) * 2 + c];
      const float ov = g_lds[(96 + j2) * 2 + c];
      const float cs = sigm(fv) * c_lds[tid] + sigm(iv) * tanhf(gv);
      c_lds[tid] = cs;
      const float hn = sigm(ov) * tanhf(cs);
      const int b = bg * 2 + c;
      __hip_atomic_store(
          h_buf + ((size_t)((t & 1) * 2 + dir) * 32 + b) * HH + slice * 32 + j2, hn,
          __ATOMIC_RELAXED, __HIP_MEMORY_SCOPE_AGENT);
      hist[(size_t)(s * BB + b) * 512 + dir * 256 + slice * 32 + j2] = hn;
    }
    __syncthreads();
    if (tid == 0) {
      __threadfence();
      __hip_atomic_store(fl + slice * 16, t + 1, __ATOMIC_RELEASE, __HIP_MEMORY_SCOPE_AGENT);
    }
  }
}

// ---------------- attention: scores over NS=16 sentence embs, softmax, g; writes comb[512:1024]
// comb[m][0:512] already holds wx (written by GEMM). grid (16 s-tiles, 32 b), 256 thr.
__global__ void att_kernel(float* __restrict__ comb, const float* __restrict__ sent) {
  __shared__ float sl[NSENT * 512];   // 32 KB
  __shared__ float wxr[512];
  __shared__ float parts[256];
  __shared__ float aw[NSENT];
  __shared__ float red0;
  const int tid = threadIdx.x;
  const int b = blockIdx.y;
  const int s0 = blockIdx.x * 32;
  for (int i = tid; i < NSENT * 512; i += 256) sl[i] = sent[(size_t)b * NSENT * 512 + i];
  __syncthreads();
  for (int si = 0; si < 32; ++si) {
    const int m = (s0 + si) * BB + b;
    float* crow = comb + (size_t)m * 1024;
    for (int i = tid; i < 512; i += 256) wxr[i] = crow[i];
    __syncthreads();
    const int n = tid >> 4, kp = tid & 15;
    float p = 0.f;
#pragma unroll 8
    for (int f = kp * 32; f < kp * 32 + 32; ++f) p = fmaf(wxr[f], sl[n * 512 + f], p);
    parts[tid] = p;
    __syncthreads();
    if (tid < NSENT) {
      float sc = 0.f;
      for (int qq = 0; qq < 16; ++qq) sc += parts[tid * 16 + qq];
      aw[tid] = sc;
    }
    __syncthreads();
    if (tid == 0) {
      float mx = aw[0];
      for (int qq = 1; qq < NSENT; ++qq) mx = fmaxf(mx, aw[qq]);
      float sm = 0.f;
      for (int qq = 0; qq < NSENT; ++qq) { float e = expf(aw[qq] - mx); aw[qq] = e; sm += e; }
      red0 = 1.f / sm;
    }
    __syncthreads();
    const float inv = red0;
    for (int f = tid; f < 512; f += 256) {
      float g = 0.f;
#pragma unroll
      for (int qq = 0; qq < NSENT; ++qq) g = fmaf(aw[qq], sl[qq * 512 + f], g);
      crow[512 + f] = g * inv;
    }
    __syncthreads();
  }
}

// ---------------- feats[m][t] = l2m[m][:] . h2t_w[t][:] + h2t_b[t]; wave per row
__global__ void feats_kernel(const float* __restrict__ l2m, const float* __restrict__ w,
                             const float* __restrict__ bias, float* __restrict__ feats) {
  const int wave = threadIdx.x >> 6, lane = threadIdx.x & 63;
  const int m = blockIdx.x * 4 + wave;
  const float* row = l2m + (size_t)m * 512;
  float rv[8];
#pragma unroll
  for (int i = 0; i < 8; ++i) rv[i] = row[lane + i * 64];
  for (int t = 0; t < TT; ++t) {
    const float* wr = w + t * 512;
    float p = 0.f;
#pragma unroll
    for (int i = 0; i < 8; ++i) p = fmaf(rv[i], wr[lane + i * 64], p);
#pragma unroll
    for (int off = 32; off; off >>= 1) p += __shfl_down(p, off);
    if (lane == 0) feats[(size_t)m * TT + t] = p + bias[t];
  }
}

// ---------------- viterbi per batch; 1 wave, whole DP in LDS
__global__ void viterbi_kernel(const float* __restrict__ feats, const float* __restrict__ trans,
                               int* __restrict__ out) {
  __shared__ float flds[SS * TT];
  __shared__ unsigned char bp[SS * TT];
  __shared__ float tr[TT * TT];
  __shared__ float fv[TT];
  __shared__ float tv[TT];
  __shared__ int pathS[SS];
  const int b = blockIdx.x, tid = threadIdx.x;
  for (int i = tid; i < SS * TT; i += 64) {
    int s = i / TT, t = i - s * TT;
    flds[i] = feats[(size_t)(s * BB + b) * TT + t];
  }
  for (int i = tid; i < TT * TT; i += 64) tr[i] = trans[i];
  if (tid < TT) fv[tid] = (tid == TAG_START) ? 0.f : -10000.f;
  __syncthreads();
  for (int s = 0; s < SS; ++s) {
    float nf = 0.f;
    if (tid < TT) {
      float mx = -1e30f;
      int bj = 0;
#pragma unroll
      for (int jj = 0; jj < TT; ++jj) {
        float v = fv[jj] + tr[tid * TT + jj];
        if (v > mx) { mx = v; bj = jj; }
      }
      nf = mx + flds[s * TT + tid];
      bp[s * TT + tid] = (unsigned char)bj;
    }
    __syncthreads();
    if (tid < TT) fv[tid] = nf;
    __syncthreads();
  }
  if (tid < TT) tv[tid] = fv[tid] + tr[TAG_STOP * TT + tid];
  __syncthreads();
  if (tid == 0) {
    int best = 0;
    float mx = tv[0];
    for (int jj = 1; jj < TT; ++jj)
      if (tv[jj] > mx) { mx = tv[jj]; best = jj; }
    pathS[SS - 1] = best;
    for (int s = SS - 1; s > 0; --s) { best = bp[s * TT + best]; pathS[s - 1] = best; }
  }
  __syncthreads();
  for (int s = tid; s < SS; s += 64) out[b * SS + s] = pathS[s];
}

// ---------------- workspace layout (bytes) — total 240,156,672 < 256 MB ----------------
#define OFF_XP    ((size_t)0)               // 2*16384*1024*4 = 134217728
#define OFF_COMB  ((size_t)134217728)       // 16384*1024*4 = 67108864 (X1 and l2m alias here)
#define OFF_WORD  ((size_t)201326592)       // 16384*512*4  = 33554432
#define OFF_WT1   ((size_t)234881024)       // 2097152
#define OFF_WT2   ((size_t)236978176)       // 2097152
#define OFF_FEATS ((size_t)239075328)       // 786432
#define OFF_HB1   ((size_t)239861760)       // 131072
#define OFF_HB2   ((size_t)239992832)       // 131072
#define OFF_FL1   ((size_t)240123904)       // 16384
#define OFF_FL2   ((size_t)240140288)       // 16384

extern "C" void kernel_launch(void* const* d_in, const int* in_sizes, int n_in,
                              void* d_out, int out_size, void* d_ws, size_t ws_size,
                              hipStream_t stream) {
  const int* inputs  = (const int*)d_in[0];
  const float* sent  = (const float*)d_in[1];
  const float* emb   = (const float*)d_in[2];
  const float* l1wih = (const float*)d_in[3];
  const float* l1whh = (const float*)d_in[4];
  const float* l1b   = (const float*)d_in[5];
  const float* l2wih = (const float*)d_in[6];
  const float* l2whh = (const float*)d_in[7];
  const float* l2b   = (const float*)d_in[8];
  const float* attW  = (const float*)d_in[9];
  const float* h2tw  = (const float*)d_in[10];
  const float* h2tb  = (const float*)d_in[11];
  const float* trans = (const float*)d_in[12];
  int* out = (int*)d_out;
  char* ws = (char*)d_ws;

  float* Xp    = (float*)(ws + OFF_XP);
  float* comb  = (float*)(ws + OFF_COMB);
  float* word  = (float*)(ws + OFF_WORD);
  float* X1    = comb;   // X1 dead before comb is written (wx GEMM reads word only)
  float* l2m   = comb;   // comb dead before rec2 writes l2m
  float* wt1   = (float*)(ws + OFF_WT1);
  float* wt2   = (float*)(ws + OFF_WT2);
  float* feats = (float*)(ws + OFF_FEATS);
  float* hb1   = (float*)(ws + OFF_HB1);
  float* hb2   = (float*)(ws + OFF_HB2);
  int* fl1     = (int*)(ws + OFF_FL1);
  int* fl2     = (int*)(ws + OFF_FL2);

  // zero h_buf slots + flags (hb1,hb2,fl1,fl2 contiguous: 131072*2 + 16384*2)
  hipMemsetAsync(ws + OFF_HB1, 0, 131072 * 2 + 16384 * 2, stream);

  prep_whh<<<2048, 256, 0, stream>>>(l1whh, wt1);
  prep_whh<<<2048, 256, 0, stream>>>(l2whh, wt2);
  embed_kernel<<<MM, 64, 0, stream>>>(inputs, emb, X1);
  for (int d = 0; d < 2; ++d)
    gemm_nt<<<dim3(16, 256), 256, 0, stream>>>(X1, l1wih + (size_t)d * GG * DD,
                                               l1b + d * GG, Xp + (size_t)d * MM * GG,
                                               DD, GG);
  rec_kernel<<<256, 128, 0, stream>>>(Xp, wt1, word, hb1, fl1);
  gemm_nt<<<dim3(8, 256), 256, 0, stream>>>(word, attW, nullptr, comb, 512, 1024);
  att_kernel<<<dim3(16, 32), 256, 0, stream>>>(comb, sent);
  for (int d = 0; d < 2; ++d)
    gemm_nt<<<dim3(16, 256), 256, 0, stream>>>(comb, l2wih + (size_t)d * GG * GG,
                                               l2b + d * GG, Xp + (size_t)d * MM * GG,
                                               GG, GG);
  rec_kernel<<<256, 128, 0, stream>>>(Xp, wt2, l2m, hb2, fl2);
  feats_kernel<<<MM / 4, 256, 0, stream>>>(l2m, h2tw, h2tb, feats);
  viterbi_kernel<<<BB, 64, 0, stream>>>(feats, trans, out);
}

// Round 3
// 7200.056 us; speedup vs baseline: 2.0834x; 2.0834x over previous
//
#include <hip/hip_runtime.h>
#include <hip/hip_bf16.h>

// Problem constants
#define BB 32
#define SS 512
#define DD 256
#define HH 256
#define GG 1024          // 4*H
#define MM (SS*BB)       // 16384 rows, m = s*32 + b
#define NSENT 16
#define TT 12
#define TAG_START 10
#define TAG_STOP 11

__device__ __forceinline__ float sigm(float x) { return 1.f / (1.f + expf(-x)); }

// ---------------- embed gather: X1[m][d] = embed[inputs[b][s]][d], m = s*32+b
__global__ void embed_kernel(const int* __restrict__ toks, const float* __restrict__ emb,
                             float* __restrict__ X1) {
  int m = blockIdx.x;
  int s = m >> 5, b = m & 31;
  int tok = toks[b * SS + s];
  ((float4*)(X1 + (size_t)m * DD))[threadIdx.x] =
      ((const float4*)(emb + (size_t)tok * DD))[threadIdx.x];
}

// ---------------- fp32 NT GEMM: C[M,N] = A[M,K] @ W[N,K]^T + bias, 64x64 tile
// LDS leading dim padded 64->68: staging writes land 2-way max (free), b128 reads
// stay 16B-aligned (68*4=272=17*16) and conflict-free.
__launch_bounds__(256)
__global__ void gemm_nt(const float* __restrict__ A, const float* __restrict__ W,
                        const float* __restrict__ bias, float* __restrict__ C,
                        int K, int ldC) {
  __shared__ float As[16 * 68];
  __shared__ float Ws[16 * 68];
  const int tid = threadIdx.x;
  const int n0 = blockIdx.x * 64, m0 = blockIdx.y * 64;
  const int row = tid >> 2, q = tid & 3;
  const int tn = tid & 15, tm = tid >> 4;
  float acc[4][4] = {};
  for (int kk = 0; kk < K; kk += 16) {
    float4 a = *(const float4*)(A + (size_t)(m0 + row) * K + kk + q * 4);
    float4 w = *(const float4*)(W + (size_t)(n0 + row) * K + kk + q * 4);
    As[(q * 4 + 0) * 68 + row] = a.x; As[(q * 4 + 1) * 68 + row] = a.y;
    As[(q * 4 + 2) * 68 + row] = a.z; As[(q * 4 + 3) * 68 + row] = a.w;
    Ws[(q * 4 + 0) * 68 + row] = w.x; Ws[(q * 4 + 1) * 68 + row] = w.y;
    Ws[(q * 4 + 2) * 68 + row] = w.z; Ws[(q * 4 + 3) * 68 + row] = w.w;
    __syncthreads();
#pragma unroll
    for (int kl = 0; kl < 16; ++kl) {
      const float4 av = *(const float4*)(As + kl * 68 + tm * 4);
      const float4 wv = *(const float4*)(Ws + kl * 68 + tn * 4);
      const float am[4] = {av.x, av.y, av.z, av.w};
      const float wm[4] = {wv.x, wv.y, wv.z, wv.w};
#pragma unroll
      for (int i = 0; i < 4; ++i)
#pragma unroll
        for (int j = 0; j < 4; ++j) acc[i][j] = fmaf(am[i], wm[j], acc[i][j]);
    }
    __syncthreads();
  }
  float4 bz = make_float4(0.f, 0.f, 0.f, 0.f);
  if (bias) bz = *(const float4*)(bias + n0 + tn * 4);
#pragma unroll
  for (int i = 0; i < 4; ++i) {
    float4 o = make_float4(acc[i][0] + bz.x, acc[i][1] + bz.y,
                           acc[i][2] + bz.z, acc[i][3] + bz.w);
    *(float4*)(C + (size_t)(m0 + tm * 4 + i) * ldC + n0 + tn * 4) = o;
  }
}

// ---------------- whh repack: whh_p[dir][slice][k][r] = whh[dir][g][k],
//                  r = gate*32 + j, g = gate*256 + slice*32 + j
__global__ void prep_whh(const float* __restrict__ whh, float* __restrict__ out) {
  int idx = blockIdx.x * 256 + threadIdx.x;        // 2*8*256*128 = 524288
  int r = idx & 127;
  int k = (idx >> 7) & 255;
  int sl = (idx >> 15) & 7;
  int dir = idx >> 18;
  int g = (r >> 5) * 256 + sl * 32 + (r & 31);
  out[idx] = whh[(size_t)(dir * GG + g) * HH + k];
}

// ---------------- LSTM recurrence (one layer, both dirs).
// grid = 256: bid = (dir + 2*bg) + 32*slice  -> 8-wg sync group (dir,bg) shares bid%8,
// landing on one XCD under round-robin (perf heuristic only).
// Sync protocol: ALL h_buf/flag traffic is RELAXED agent-scope atomic (sc0/sc1 ->
// performed at the device coherence point, correct regardless of XCD mapping).
// Ordering: __syncthreads() lowers with s_waitcnt vmcnt(0) before s_barrier, so the
// h stores are committed before tid0's flag store (hipBLASLt GSU pattern). No
// threadfence / acquire -> no per-step cache writeback/invalidate instructions.
__launch_bounds__(128)
__global__ void rec_kernel(const float* __restrict__ Xp, const float* __restrict__ whh_p,
                           float* __restrict__ hist, float* __restrict__ h_buf,
                           int* __restrict__ flags) {
  __shared__ float lds[33600];       // 134400 bytes static -> 1 wg/CU
  float* whh_lds = lds;              // [k*128 + r], 32768 floats
  float* h_lds = lds + 32768;        // [k*2 + c],   512
  float* g_lds = lds + 33280;        // [r*2 + c],   256
  float* c_lds = lds + 33536;        // [j*2 + c],   64
  const int tid = threadIdx.x;
  const int bid = blockIdx.x;
  const int slice = bid >> 5;
  const int db = bid & 31;
  const int dir = db & 1;
  const int bg = db >> 1;
  const float* wp = whh_p + (size_t)(dir * 8 + slice) * 256 * 128;
  for (int i = tid; i < 32768; i += 128) whh_lds[i] = wp[i];
  if (tid < 64) c_lds[tid] = 0.f;
  int* fl = flags + (dir * 16 + bg) * 8 * 16;      // 16-int padded flags
  const float* XpD = Xp + (size_t)dir * MM * GG;
  const int gate = tid >> 5, j = tid & 31;
  const int gcol = gate * 256 + slice * 32 + j;
  __syncthreads();
  for (int t = 0; t < SS; ++t) {
    const int s = dir ? (SS - 1 - t) : t;
    // prefetch this step's gate inputs BEFORE the poll: HBM latency hides under spin
    const int m0 = s * BB + bg * 2;
    const float xp0 = XpD[(size_t)m0 * GG + gcol];
    const float xp1 = XpD[(size_t)(m0 + 1) * GG + gcol];
    if (tid < 8) {
      while (__hip_atomic_load(fl + tid * 16, __ATOMIC_RELAXED, __HIP_MEMORY_SCOPE_AGENT) < t)
        __builtin_amdgcn_s_sleep(1);
    }
    __syncthreads();
    const int slotR = (t & 1) ^ 1;                 // slot holding h_{t-1}
    for (int i = tid; i < 512; i += 128) {
      const int c = i >> 8, k = i & 255;
      float v = __hip_atomic_load(
          h_buf + ((size_t)(slotR * 2 + dir) * 32 + bg * 2 + c) * HH + k,
          __ATOMIC_RELAXED, __HIP_MEMORY_SCOPE_AGENT);
      h_lds[k * 2 + c] = v;
    }
    __syncthreads();
    float acc0 = 0.f, acc1 = 0.f;
#pragma unroll 8
    for (int k = 0; k < 256; ++k) {
      const float w = whh_lds[k * 128 + tid];
      acc0 = fmaf(w, h_lds[2 * k], acc0);
      acc1 = fmaf(w, h_lds[2 * k + 1], acc1);
    }
    g_lds[tid * 2] = acc0 + xp0;
    g_lds[tid * 2 + 1] = acc1 + xp1;
    __syncthreads();
    if (tid < 64) {
      const int j2 = tid >> 1, c = tid & 1;
      const float iv = g_lds[(j2) * 2 + c];
      const float fv = g_lds[(32 + j2) * 2 + c];
      const float gv = g_lds[(64 + j2) * 2 + c];
      const float ov = g_lds[(96 + j2) * 2 + c];
      const float cs = sigm(fv) * c_lds[tid] + sigm(iv) * tanhf(gv);
      c_lds[tid] = cs;
      const float hn = sigm(ov) * tanhf(cs);
      const int b = bg * 2 + c;
      __hip_atomic_store(
          h_buf + ((size_t)((t & 1) * 2 + dir) * 32 + b) * HH + slice * 32 + j2, hn,
          __ATOMIC_RELAXED, __HIP_MEMORY_SCOPE_AGENT);
      hist[(size_t)(s * BB + b) * 512 + dir * 256 + slice * 32 + j2] = hn;
    }
    __syncthreads();   // drains vmcnt(0): h stores committed at coherence point
    if (tid == 0) {
      __hip_atomic_store(fl + slice * 16, t + 1, __ATOMIC_RELAXED, __HIP_MEMORY_SCOPE_AGENT);
    }
  }
}

// ---------------- attention: scores over NS=16 sentence embs, softmax, g; writes comb[512:1024]
// comb[m][0:512] already holds wx (written by GEMM). grid (16 s-tiles, 32 b), 256 thr.
__global__ void att_kernel(float* __restrict__ comb, const float* __restrict__ sent) {
  __shared__ float sl[NSENT * 512];   // 32 KB
  __shared__ float wxr[512];
  __shared__ float parts[256];
  __shared__ float aw[NSENT];
  __shared__ float red0;
  const int tid = threadIdx.x;
  const int b = blockIdx.y;
  const int s0 = blockIdx.x * 32;
  for (int i = tid; i < NSENT * 512; i += 256) sl[i] = sent[(size_t)b * NSENT * 512 + i];
  __syncthreads();
  for (int si = 0; si < 32; ++si) {
    const int m = (s0 + si) * BB + b;
    float* crow = comb + (size_t)m * 1024;
    for (int i = tid; i < 512; i += 256) wxr[i] = crow[i];
    __syncthreads();
    const int n = tid >> 4, kp = tid & 15;
    float p = 0.f;
#pragma unroll 8
    for (int f = kp * 32; f < kp * 32 + 32; ++f) p = fmaf(wxr[f], sl[n * 512 + f], p);
    parts[tid] = p;
    __syncthreads();
    if (tid < NSENT) {
      float sc = 0.f;
      for (int qq = 0; qq < 16; ++qq) sc += parts[tid * 16 + qq];
      aw[tid] = sc;
    }
    __syncthreads();
    if (tid == 0) {
      float mx = aw[0];
      for (int qq = 1; qq < NSENT; ++qq) mx = fmaxf(mx, aw[qq]);
      float sm = 0.f;
      for (int qq = 0; qq < NSENT; ++qq) { float e = expf(aw[qq] - mx); aw[qq] = e; sm += e; }
      red0 = 1.f / sm;
    }
    __syncthreads();
    const float inv = red0;
    for (int f = tid; f < 512; f += 256) {
      float g = 0.f;
#pragma unroll
      for (int qq = 0; qq < NSENT; ++qq) g = fmaf(aw[qq], sl[qq * 512 + f], g);
      crow[512 + f] = g * inv;
    }
    __syncthreads();
  }
}

// ---------------- feats[m][t] = l2m[m][:] . h2t_w[t][:] + h2t_b[t]; wave per row
__global__ void feats_kernel(const float* __restrict__ l2m, const float* __restrict__ w,
                             const float* __restrict__ bias, float* __restrict__ feats) {
  const int wave = threadIdx.x >> 6, lane = threadIdx.x & 63;
  const int m = blockIdx.x * 4 + wave;
  const float* row = l2m + (size_t)m * 512;
  float rv[8];
#pragma unroll
  for (int i = 0; i < 8; ++i) rv[i] = row[lane + i * 64];
  for (int t = 0; t < TT; ++t) {
    const float* wr = w + t * 512;
    float p = 0.f;
#pragma unroll
    for (int i = 0; i < 8; ++i) p = fmaf(rv[i], wr[lane + i * 64], p);
#pragma unroll
    for (int off = 32; off; off >>= 1) p += __shfl_down(p, off);
    if (lane == 0) feats[(size_t)m * TT + t] = p + bias[t];
  }
}

// ---------------- viterbi per batch; 1 wave, whole DP in LDS
__global__ void viterbi_kernel(const float* __restrict__ feats, const float* __restrict__ trans,
                               int* __restrict__ out) {
  __shared__ float flds[SS * TT];
  __shared__ unsigned char bp[SS * TT];
  __shared__ float tr[TT * TT];
  __shared__ float fv[TT];
  __shared__ float tv[TT];
  __shared__ int pathS[SS];
  const int b = blockIdx.x, tid = threadIdx.x;
  for (int i = tid; i < SS * TT; i += 64) {
    int s = i / TT, t = i - s * TT;
    flds[i] = feats[(size_t)(s * BB + b) * TT + t];
  }
  for (int i = tid; i < TT * TT; i += 64) tr[i] = trans[i];
  if (tid < TT) fv[tid] = (tid == TAG_START) ? 0.f : -10000.f;
  __syncthreads();
  for (int s = 0; s < SS; ++s) {
    float nf = 0.f;
    if (tid < TT) {
      float mx = -1e30f;
      int bj = 0;
#pragma unroll
      for (int jj = 0; jj < TT; ++jj) {
        float v = fv[jj] + tr[tid * TT + jj];
        if (v > mx) { mx = v; bj = jj; }
      }
      nf = mx + flds[s * TT + tid];
      bp[s * TT + tid] = (unsigned char)bj;
    }
    __syncthreads();
    if (tid < TT) fv[tid] = nf;
    __syncthreads();
  }
  if (tid < TT) tv[tid] = fv[tid] + tr[TAG_STOP * TT + tid];
  __syncthreads();
  if (tid == 0) {
    int best = 0;
    float mx = tv[0];
    for (int jj = 1; jj < TT; ++jj)
      if (tv[jj] > mx) { mx = tv[jj]; best = jj; }
    pathS[SS - 1] = best;
    for (int s = SS - 1; s > 0; --s) { best = bp[s * TT + best]; pathS[s - 1] = best; }
  }
  __syncthreads();
  for (int s = tid; s < SS; s += 64) out[b * SS + s] = pathS[s];
}

// ---------------- workspace layout (bytes) — total 240,156,672 < 256 MB ----------------
#define OFF_XP    ((size_t)0)               // 2*16384*1024*4 = 134217728
#define OFF_COMB  ((size_t)134217728)       // 16384*1024*4 = 67108864 (X1 and l2m alias here)
#define OFF_WORD  ((size_t)201326592)       // 16384*512*4  = 33554432
#define OFF_WT1   ((size_t)234881024)       // 2097152
#define OFF_WT2   ((size_t)236978176)       // 2097152
#define OFF_FEATS ((size_t)239075328)       // 786432
#define OFF_HB1   ((size_t)239861760)       // 131072
#define OFF_HB2   ((size_t)239992832)       // 131072
#define OFF_FL1   ((size_t)240123904)       // 16384
#define OFF_FL2   ((size_t)240140288)       // 16384

extern "C" void kernel_launch(void* const* d_in, const int* in_sizes, int n_in,
                              void* d_out, int out_size, void* d_ws, size_t ws_size,
                              hipStream_t stream) {
  const int* inputs  = (const int*)d_in[0];
  const float* sent  = (const float*)d_in[1];
  const float* emb   = (const float*)d_in[2];
  const float* l1wih = (const float*)d_in[3];
  const float* l1whh = (const float*)d_in[4];
  const float* l1b   = (const float*)d_in[5];
  const float* l2wih = (const float*)d_in[6];
  const float* l2whh = (const float*)d_in[7];
  const float* l2b   = (const float*)d_in[8];
  const float* attW  = (const float*)d_in[9];
  const float* h2tw  = (const float*)d_in[10];
  const float* h2tb  = (const float*)d_in[11];
  const float* trans = (const float*)d_in[12];
  int* out = (int*)d_out;
  char* ws = (char*)d_ws;

  float* Xp    = (float*)(ws + OFF_XP);
  float* comb  = (float*)(ws + OFF_COMB);
  float* word  = (float*)(ws + OFF_WORD);
  float* X1    = comb;   // X1 dead before comb is written (wx GEMM reads word only)
  float* l2m   = comb;   // comb dead before rec2 writes l2m
  float* wt1   = (float*)(ws + OFF_WT1);
  float* wt2   = (float*)(ws + OFF_WT2);
  float* feats = (float*)(ws + OFF_FEATS);
  float* hb1   = (float*)(ws + OFF_HB1);
  float* hb2   = (float*)(ws + OFF_HB2);
  int* fl1     = (int*)(ws + OFF_FL1);
  int* fl2     = (int*)(ws + OFF_FL2);

  // zero h_buf slots + flags (hb1,hb2,fl1,fl2 contiguous: 131072*2 + 16384*2)
  hipMemsetAsync(ws + OFF_HB1, 0, 131072 * 2 + 16384 * 2, stream);

  prep_whh<<<2048, 256, 0, stream>>>(l1whh, wt1);
  prep_whh<<<2048, 256, 0, stream>>>(l2whh, wt2);
  embed_kernel<<<MM, 64, 0, stream>>>(inputs, emb, X1);
  for (int d = 0; d < 2; ++d)
    gemm_nt<<<dim3(16, 256), 256, 0, stream>>>(X1, l1wih + (size_t)d * GG * DD,
                                               l1b + d * GG, Xp + (size_t)d * MM * GG,
                                               DD, GG);
  rec_kernel<<<256, 128, 0, stream>>>(Xp, wt1, word, hb1, fl1);
  gemm_nt<<<dim3(8, 256), 256, 0, stream>>>(word, attW, nullptr, comb, 512, 1024);
  att_kernel<<<dim3(16, 32), 256, 0, stream>>>(comb, sent);
  for (int d = 0; d < 2; ++d)
    gemm_nt<<<dim3(16, 256), 256, 0, stream>>>(comb, l2wih + (size_t)d * GG * GG,
                                               l2b + d * GG, Xp + (size_t)d * MM * GG,
                                               GG, GG);
  rec_kernel<<<256, 128, 0, stream>>>(Xp, wt2, l2m, hb2, fl2);
  feats_kernel<<<MM / 4, 256, 0, stream>>>(l2m, h2tw, h2tb, feats);
  viterbi_kernel<<<BB, 64, 0, stream>>>(feats, trans, out);
}